// Round 5
// baseline (759.063 us; speedup 1.0000x reference)
//
#include <hip/hip_runtime.h>

// Problem constants
#define CC 64
#define HWSZ 16384                 // 128*128
#define NSITES 524288              // 32*128*128
#define NTILES (NSITES / 64)       // 8192 tiles of 64 sites

typedef float f32x4 __attribute__((ext_vector_type(4)));

#define FLAG_A (1ull << 62)
#define FLAG_P (2ull << 62)

static __device__ __forceinline__ unsigned int waveSum(unsigned int v) {
#pragma unroll
    for (int o = 32; o > 0; o >>= 1) v += (unsigned int)__shfl_xor((int)v, o, 64);
    return v;
}

// ---------------------------------------------------------------------------
// Reset lookback state (statuses + ticket) — must run every call: harness
// does not re-poison ws between graph replays and launch must be stateless.
// ---------------------------------------------------------------------------
__global__ __launch_bounds__(256) void k_init(unsigned long long* __restrict__ status,
                                              unsigned int* __restrict__ ticket) {
    const int i = blockIdx.x * 256 + threadIdx.x;
    if (i < NTILES) status[i] = 0ull;
    if (i == 0) *ticket = 0u;
}

// ---------------------------------------------------------------------------
// Single-pass fused flags + scan (decoupled lookback) + scatter.
// Block = 256 threads handles one 64-site tile:
//   stage [64 sites][64 ch] in LDS (stride 65) while accumulating per-site
//   |x| partial sums -> wave0 reduces, __ballot -> 64-bit activity word ->
//   publish aggregate, wave-parallel lookback for exclusive prefix ->
//   emit active rows compacted to front, inactive rows as zeros to the
//   mirrored padding slot (row NSITES-1-j for the j-th inactive site).
// Tiles are claimed via an atomic ticket so lookback ordering follows
// execution order (deadlock-free regardless of dispatch order).
// ---------------------------------------------------------------------------
__global__ __launch_bounds__(256) void k_fused(const float* __restrict__ x,
                                               unsigned long long* __restrict__ status,
                                               unsigned int* __restrict__ ticket,
                                               float* __restrict__ out,
                                               float* __restrict__ out_count_f) {
    __shared__ float tile[64 * 65];
    __shared__ float psf[16 * 64];
    __shared__ unsigned long long sh_word;
    __shared__ unsigned int sh_excl;
    __shared__ unsigned int sh_vt;

    const int t = threadIdx.x;
    if (t == 0) sh_vt = atomicAdd(ticket, 1u);
    __syncthreads();
    const unsigned int vt = sh_vt;  // virtual tile id, in claim order

    const int g = t >> 4;    // 0..15 channel group
    const int l16 = t & 15;  // 0..15 site quad
    const long long site0 = (long long)vt * 64;
    const int b = (int)(site0 >> 14);                  // 64 | HWSZ, no b straddle
    const int hw0 = (int)(site0 & (HWSZ - 1)) + 4 * l16;

    // ---- stage + per-site |x| partial sums
    f32x4 acc = {0.f, 0.f, 0.f, 0.f};
#pragma unroll
    for (int i = 0; i < 4; ++i) {
        const int c = g + 16 * i;
        const f32x4 v = *reinterpret_cast<const f32x4*>(x + ((size_t)b * CC + c) * HWSZ + hw0);
        tile[(4 * l16 + 0) * 65 + c] = v.x;
        tile[(4 * l16 + 1) * 65 + c] = v.y;
        tile[(4 * l16 + 2) * 65 + c] = v.z;
        tile[(4 * l16 + 3) * 65 + c] = v.w;
        acc.x += fabsf(v.x);
        acc.y += fabsf(v.y);
        acc.z += fabsf(v.z);
        acc.w += fabsf(v.w);
    }
    {
        const int base = g * 64 + 4 * l16;   // psf[g][site]
        psf[base + 0] = acc.x;
        psf[base + 1] = acc.y;
        psf[base + 2] = acc.z;
        psf[base + 3] = acc.w;
    }
    __syncthreads();

    // ---- wave 0: activity word, publish aggregate, lookback
    if (t < 64) {
        float s = 0.f;
#pragma unroll
        for (int gg = 0; gg < 16; ++gg) s += psf[gg * 64 + t];  // consecutive lanes, no conflict
        const unsigned long long w = __ballot(s != 0.f);
        const unsigned int agg = (unsigned int)__popcll(w);
        if (t == 0) {
            sh_word = w;
            if (vt != 0)
                __hip_atomic_store(&status[vt], FLAG_A | (unsigned long long)agg,
                                   __ATOMIC_RELEASE, __HIP_MEMORY_SCOPE_AGENT);
        }
        // wave-parallel lookback: 64 predecessors per round
        unsigned int excl = 0;
        int hi = (int)vt;
        while (hi > 0) {
            const int lo = (hi >= 64) ? hi - 64 : 0;
            const int n = hi - lo;
            unsigned long long s64;
            for (;;) {
                s64 = (t < n) ? __hip_atomic_load(&status[lo + t], __ATOMIC_ACQUIRE,
                                                  __HIP_MEMORY_SCOPE_AGENT)
                              : FLAG_A;  // pad lanes: aggregate 0
                if (__all((int)((s64 >> 62) != 0ull))) break;
                __builtin_amdgcn_s_sleep(2);
            }
            const unsigned long long pmask = __ballot((int)((s64 >> 62) == 2ull));
            if (pmask != 0ull) {
                const int pl = 63 - __clzll((long long)pmask);  // highest-index P
                const unsigned int contrib = (t >= pl && t < n) ? (unsigned int)s64 : 0u;
                excl += waveSum(contrib);  // P's inclusive + A's after it
                break;
            } else {
                const unsigned int contrib = (t < n) ? (unsigned int)s64 : 0u;
                excl += waveSum(contrib);
                hi = lo;
            }
        }
        if (t == 0) {
            const unsigned int incl = excl + agg;
            __hip_atomic_store(&status[vt], FLAG_P | (unsigned long long)incl,
                               __ATOMIC_RELEASE, __HIP_MEMORY_SCOPE_AGENT);
            sh_excl = excl;
            if (vt == NTILES - 1) *out_count_f = (float)incl;  // total active count
        }
    }
    __syncthreads();

    const unsigned long long wflag = sh_word;
    const unsigned int woff = sh_excl;                 // actives before this tile
    const unsigned int iwoff = vt * 64u - woff;        // inactives before this tile

    // ---- emit: group g handles rows g, g+16, g+32, g+48
#pragma unroll
    for (int i = 0; i < 4; ++i) {
        const int r = g + 16 * i;
        const unsigned long long before = wflag & ((1ull << r) - 1ull);  // r==0 -> 0
        const unsigned int ab = (unsigned int)__popcll(before);
        if ((wflag >> r) & 1ull) {
            const unsigned int pos = woff + ab;
            f32x4 v;
            v.x = tile[r * 65 + 4 * l16 + 0];
            v.y = tile[r * 65 + 4 * l16 + 1];
            v.z = tile[r * 65 + 4 * l16 + 2];
            v.w = tile[r * 65 + 4 * l16 + 3];
            __builtin_nontemporal_store(
                v, reinterpret_cast<f32x4*>(out + (size_t)pos * CC + 4 * l16));
        } else {
            const unsigned int ipos = iwoff + ((unsigned int)r - ab);
            const size_t zrow = (size_t)(NSITES - 1) - ipos;
            const f32x4 z = {0.f, 0.f, 0.f, 0.f};
            __builtin_nontemporal_store(
                z, reinterpret_cast<f32x4*>(out + zrow * CC + 4 * l16));
        }
    }
}

extern "C" void kernel_launch(void* const* d_in, const int* in_sizes, int n_in,
                              void* d_out, int out_size, void* d_ws, size_t ws_size,
                              hipStream_t stream) {
    (void)in_sizes; (void)n_in; (void)out_size; (void)ws_size;
    const float* x = (const float*)d_in[0];
    float* out = (float*)d_out;

    char* ws = (char*)d_ws;
    unsigned long long* status = (unsigned long long*)ws;          // 64 KiB
    unsigned int* ticket = (unsigned int*)(ws + NTILES * 8);       // 4 B

    float* out_count_f = out + (size_t)NSITES * CC;  // second tuple output

    hipLaunchKernelGGL(k_init, dim3((NTILES + 255) / 256), dim3(256), 0, stream, status, ticket);
    hipLaunchKernelGGL(k_fused, dim3(NTILES), dim3(256), 0, stream, x, status, ticket, out,
                       out_count_f);
}

// Round 6
// 69.417 us; speedup vs baseline: 10.9348x; 10.9348x over previous
//
#include <hip/hip_runtime.h>

// Problem constants
#define CC 64
#define HWSZ 16384                 // 128*128
#define NSITES 524288              // 32*128*128
#define NWORDS (NSITES / 64)       // 8192

typedef float f32x4 __attribute__((ext_vector_type(4)));

// ---------------------------------------------------------------------------
// Kernel 1: per-site activity flags, packed 64 sites per uint64 word.
// Block = 256 threads handles 1024 consecutive sites (4 sites/thread, float4).
// Grid = 512 blocks. Fully coalesced; also warms L3 with x for k_scatter.
// ---------------------------------------------------------------------------
__global__ __launch_bounds__(256) void k_flags(const float* __restrict__ x,
                                               unsigned long long* __restrict__ flags) {
    const int t = threadIdx.x;
    const int site0 = blockIdx.x * 1024 + 4 * t;   // 4 consecutive sites
    const int b = site0 >> 14;                     // blocks never straddle b
    const int hw = site0 & (HWSZ - 1);
    const float* p = x + ((size_t)b * CC) * HWSZ + hw;

    float a0 = 0.f, a1 = 0.f, a2 = 0.f, a3 = 0.f;
#pragma unroll 8
    for (int c = 0; c < CC; ++c) {
        const f32x4 v = *reinterpret_cast<const f32x4*>(p + (size_t)c * HWSZ);
        a0 += fabsf(v.x);
        a1 += fabsf(v.y);
        a2 += fabsf(v.z);
        a3 += fabsf(v.w);
    }
    unsigned int nib = (unsigned int)(a0 != 0.f) | ((unsigned int)(a1 != 0.f) << 1) |
                       ((unsigned int)(a2 != 0.f) << 2) | ((unsigned int)(a3 != 0.f) << 3);

    __shared__ unsigned int nibs[256];
    nibs[t] = nib;
    __syncthreads();
    if (t < 16) {
        unsigned long long w = 0ull;
#pragma unroll
        for (int j = 0; j < 16; ++j)
            w |= (unsigned long long)nibs[16 * t + j] << (4 * j);
        flags[(size_t)blockIdx.x * 16 + t] = w;
    }
}

// ---------------------------------------------------------------------------
// Kernel 2: exclusive scan of per-word popcounts. Single block, 1024 threads,
// 8 words/thread. shfl-based: wave-inclusive scan (no barriers) + 16 wave
// totals via LDS broadcast; 1 barrier total. Writes word offsets + count.
// ---------------------------------------------------------------------------
__global__ __launch_bounds__(1024) void k_scan(const unsigned long long* __restrict__ flags,
                                               unsigned int* __restrict__ wordOffsets,
                                               float* __restrict__ out_count_f) {
    __shared__ unsigned int wtot[16];
    const int t = threadIdx.x;
    const int wave = t >> 6;
    const int lane = t & 63;
    const int base = 8 * t;

    unsigned int c[8];
    unsigned int s = 0;
#pragma unroll
    for (int j = 0; j < 8; ++j) {
        c[j] = (unsigned int)__popcll(flags[base + j]);
        s += c[j];
    }
    // inclusive wave scan of s (64-wide)
    unsigned int incl = s;
#pragma unroll
    for (int o = 1; o < 64; o <<= 1) {
        const unsigned int n = (unsigned int)__shfl_up((int)incl, o, 64);
        if (lane >= o) incl += n;
    }
    if (lane == 63) wtot[wave] = incl;
    __syncthreads();
    unsigned int wexcl = 0;
    for (int wv = 0; wv < wave; ++wv) wexcl += wtot[wv];  // LDS broadcast reads

    unsigned int run = wexcl + (incl - s);  // exclusive prefix for this thread
#pragma unroll
    for (int j = 0; j < 8; ++j) {
        wordOffsets[base + j] = run;
        run += c[j];
    }
    if (t == 1023) *out_count_f = (float)run;  // total active count (tuple output 2)
}

// ---------------------------------------------------------------------------
// Kernel 3: gather/scatter of ALL rows (active -> compacted front, inactive ->
// zero row via the mirror map: j-th inactive site owns padding row NSITES-1-j).
// Every output row written exactly once; no separate zero pass. Block = 256
// threads, 4 chunks of 64 sites; [64][65] LDS tile (2-way bank aliasing = free
// on CDNA4); branchless emit: row index and value chosen by selects; 16 lanes
// x f32x4 -> contiguous 256B rows, non-temporal (write-only output, keep L3
// for x).
// ---------------------------------------------------------------------------
__global__ __launch_bounds__(256) void k_scatter(const float* __restrict__ x,
                                                 const unsigned long long* __restrict__ flags,
                                                 const unsigned int* __restrict__ wordOffsets,
                                                 float* __restrict__ out) {
    __shared__ float tile[64 * 65];
    const int t = threadIdx.x;
    const int g = t >> 4;       // 0..15 channel group
    const int l16 = t & 15;     // 0..15 site quad

    const int wi0 = blockIdx.x * 4;
    unsigned long long wf[4];
    unsigned int wo[4];
#pragma unroll
    for (int k = 0; k < 4; ++k) {
        wf[k] = flags[wi0 + k];
        wo[k] = wordOffsets[wi0 + k];
    }

    const int site_base = blockIdx.x * 256;   // 256 | HWSZ: no b straddle
    const int b = site_base >> 14;

    for (int chunk = 0; chunk < 4; ++chunk) {
        const int hw0 = ((site_base + chunk * 64) & (HWSZ - 1)) + 4 * l16;

        // ---- stage: 4 iters, 16 channels each; thread loads float4 over sites
#pragma unroll
        for (int i = 0; i < 4; ++i) {
            const int c = g + 16 * i;
            const f32x4 v =
                *reinterpret_cast<const f32x4*>(x + ((size_t)b * CC + c) * HWSZ + hw0);
            tile[(4 * l16 + 0) * 65 + c] = v.x;
            tile[(4 * l16 + 1) * 65 + c] = v.y;
            tile[(4 * l16 + 2) * 65 + c] = v.z;
            tile[(4 * l16 + 3) * 65 + c] = v.w;
        }
        __syncthreads();

        const unsigned long long wflag = wf[chunk];
        const unsigned int woff = wo[chunk];                             // actives before word
        const unsigned int iwoff = (unsigned int)(wi0 + chunk) * 64u - woff;  // inactives before

        // ---- emit: group g handles rows g, g+16, g+32, g+48 (branchless)
#pragma unroll
        for (int i = 0; i < 4; ++i) {
            const int r = g + 16 * i;
            const unsigned long long before = wflag & ((1ull << r) - 1ull);  // r==0 -> 0
            const unsigned int ab = (unsigned int)__popcll(before);
            const bool act = (wflag >> r) & 1ull;
            const size_t arow = (size_t)(woff + ab);
            const size_t zrow = (size_t)(NSITES - 1) - (size_t)(iwoff + ((unsigned int)r - ab));
            const size_t row = act ? arow : zrow;
            f32x4 v;
            v.x = tile[r * 65 + 4 * l16 + 0];
            v.y = tile[r * 65 + 4 * l16 + 1];
            v.z = tile[r * 65 + 4 * l16 + 2];
            v.w = tile[r * 65 + 4 * l16 + 3];
            const f32x4 zv = {0.f, 0.f, 0.f, 0.f};
            if (!act) v = zv;
            __builtin_nontemporal_store(
                v, reinterpret_cast<f32x4*>(out + row * CC + 4 * l16));
        }

        if (chunk < 3) __syncthreads();  // protect tile before next staging
    }
}

extern "C" void kernel_launch(void* const* d_in, const int* in_sizes, int n_in,
                              void* d_out, int out_size, void* d_ws, size_t ws_size,
                              hipStream_t stream) {
    (void)in_sizes; (void)n_in; (void)out_size; (void)ws_size;
    const float* x = (const float*)d_in[0];
    float* out = (float*)d_out;

    char* ws = (char*)d_ws;
    unsigned long long* flags = (unsigned long long*)ws;          // 64 KiB
    unsigned int* wordOffsets = (unsigned int*)(ws + 65536);      // 32 KiB

    float* out_count_f = out + (size_t)NSITES * CC;  // second tuple output

    hipLaunchKernelGGL(k_flags, dim3(NSITES / 1024), dim3(256), 0, stream, x, flags);
    hipLaunchKernelGGL(k_scan, dim3(1), dim3(1024), 0, stream, flags, wordOffsets,
                       out_count_f);
    hipLaunchKernelGGL(k_scatter, dim3(NWORDS / 4), dim3(256), 0, stream, x, flags,
                       wordOffsets, out);
}

// Round 7
// 68.831 us; speedup vs baseline: 11.0280x; 1.0085x over previous
//
#include <hip/hip_runtime.h>

// Problem constants
#define CC 64
#define HWSZ 16384                 // 128*128
#define NSITES 524288              // 32*128*128
#define NWORDS (NSITES / 64)       // 8192
#define NFB    (NWORDS / 16)       // 512 flag-blocks (one per k_flags block)

typedef float f32x4 __attribute__((ext_vector_type(4)));

static __device__ __forceinline__ unsigned int waveSum(unsigned int v) {
#pragma unroll
    for (int o = 32; o > 0; o >>= 1) v += (unsigned int)__shfl_xor((int)v, o, 64);
    return v;
}

// ---------------------------------------------------------------------------
// Kernel 1: per-site activity flags, packed 64 sites per uint64 word, plus a
// per-block popcount sum (blockSum[512]) so scatter can derive its own global
// prefix without a separate scan kernel.
// Block = 256 threads handles 1024 consecutive sites (4 sites/thread, float4).
// Grid = 512 blocks. Fully coalesced; also warms L3 with x for k_scatter.
// ---------------------------------------------------------------------------
__global__ __launch_bounds__(256) void k_flags(const float* __restrict__ x,
                                               unsigned long long* __restrict__ flags,
                                               unsigned int* __restrict__ blockSum) {
    const int t = threadIdx.x;
    const int site0 = blockIdx.x * 1024 + 4 * t;   // 4 consecutive sites
    const int b = site0 >> 14;                     // blocks never straddle b
    const int hw = site0 & (HWSZ - 1);
    const float* p = x + ((size_t)b * CC) * HWSZ + hw;

    float a0 = 0.f, a1 = 0.f, a2 = 0.f, a3 = 0.f;
#pragma unroll 8
    for (int c = 0; c < CC; ++c) {
        const f32x4 v = *reinterpret_cast<const f32x4*>(p + (size_t)c * HWSZ);
        a0 += fabsf(v.x);
        a1 += fabsf(v.y);
        a2 += fabsf(v.z);
        a3 += fabsf(v.w);
    }
    unsigned int nib = (unsigned int)(a0 != 0.f) | ((unsigned int)(a1 != 0.f) << 1) |
                       ((unsigned int)(a2 != 0.f) << 2) | ((unsigned int)(a3 != 0.f) << 3);

    __shared__ unsigned int nibs[256];
    __shared__ unsigned int pops[16];
    nibs[t] = nib;
    __syncthreads();
    if (t < 16) {
        unsigned long long w = 0ull;
#pragma unroll
        for (int j = 0; j < 16; ++j)
            w |= (unsigned long long)nibs[16 * t + j] << (4 * j);
        flags[(size_t)blockIdx.x * 16 + t] = w;
        pops[t] = (unsigned int)__popcll(w);
    }
    __syncthreads();
    if (t == 0) {
        unsigned int s = 0;
#pragma unroll
        for (int j = 0; j < 16; ++j) s += pops[j];
        blockSum[blockIdx.x] = s;
    }
}

// ---------------------------------------------------------------------------
// Kernel 2: fused scan + gather/scatter. Each block (4 words = 256 sites)
// derives its global active-prefix itself: wave 0 lane-parallel sums
// blockSum[j] for flag-blocks before it (<=511 values) plus popcounts of the
// <=12 preceding words inside its flag-block, overlapped with chunk-0 LDS
// staging by the other waves. Active rows -> compacted front; inactive rows ->
// zero row via the mirror map (j-th inactive site owns row NSITES-1-j), so
// every output row is written exactly once. [64][65] LDS tile (2-way bank
// aliasing = free). Branchless emit; 16 lanes x f32x4 -> contiguous 256B
// non-temporal row stores (write-only output, keep L3 for x). Last block
// writes the active-site count (second tuple output).
// ---------------------------------------------------------------------------
__global__ __launch_bounds__(256) void k_scatter(const float* __restrict__ x,
                                                 const unsigned long long* __restrict__ flags,
                                                 const unsigned int* __restrict__ blockSum,
                                                 float* __restrict__ out,
                                                 float* __restrict__ out_count_f) {
    __shared__ float tile[64 * 65];
    __shared__ unsigned int sh_prefix;
    const int t = threadIdx.x;
    const int g = t >> 4;       // 0..15 channel group
    const int l16 = t & 15;     // 0..15 site quad

    const int wi0 = blockIdx.x * 4;
    unsigned long long wf[4];
#pragma unroll
    for (int k = 0; k < 4; ++k) wf[k] = flags[wi0 + k];

    const int site_base = blockIdx.x * 256;   // 256 | HWSZ: no b straddle
    const int b = site_base >> 14;

    // ---- stage chunk 0 (all waves)
    {
        const int hw0 = (site_base & (HWSZ - 1)) + 4 * l16;
#pragma unroll
        for (int i = 0; i < 4; ++i) {
            const int c = g + 16 * i;
            const f32x4 v =
                *reinterpret_cast<const f32x4*>(x + ((size_t)b * CC + c) * HWSZ + hw0);
            tile[(4 * l16 + 0) * 65 + c] = v.x;
            tile[(4 * l16 + 1) * 65 + c] = v.y;
            tile[(4 * l16 + 2) * 65 + c] = v.z;
            tile[(4 * l16 + 3) * 65 + c] = v.w;
        }
    }

    // ---- wave 0: global active-prefix for this block (overlaps staging above)
    if (t < 64) {
        const int fb = blockIdx.x >> 2;          // owning flag-block
        const int npre = (blockIdx.x & 3) * 4;   // words before us inside flag-block
        unsigned int part = 0;
#pragma unroll
        for (int k = 0; k < 8; ++k) {
            const int j = t + 64 * k;
            if (j < fb) part += blockSum[j];
        }
        if (t < npre) part += (unsigned int)__popcll(flags[16 * fb + t]);
        part = waveSum(part);
        if (t == 0) sh_prefix = part;
    }
    __syncthreads();

    const unsigned int prefix = sh_prefix;
    unsigned int wo[4];
    wo[0] = prefix;
#pragma unroll
    for (int k = 1; k < 4; ++k) wo[k] = wo[k - 1] + (unsigned int)__popcll(wf[k - 1]);

    if (blockIdx.x == (NWORDS / 4 - 1) && t == 0)
        *out_count_f = (float)(wo[3] + (unsigned int)__popcll(wf[3]));  // total actives

    for (int chunk = 0; chunk < 4; ++chunk) {
        if (chunk > 0) {
            // ---- stage chunk (all waves)
            const int hw0 = ((site_base + chunk * 64) & (HWSZ - 1)) + 4 * l16;
#pragma unroll
            for (int i = 0; i < 4; ++i) {
                const int c = g + 16 * i;
                const f32x4 v =
                    *reinterpret_cast<const f32x4*>(x + ((size_t)b * CC + c) * HWSZ + hw0);
                tile[(4 * l16 + 0) * 65 + c] = v.x;
                tile[(4 * l16 + 1) * 65 + c] = v.y;
                tile[(4 * l16 + 2) * 65 + c] = v.z;
                tile[(4 * l16 + 3) * 65 + c] = v.w;
            }
            __syncthreads();
        }

        const unsigned long long wflag = wf[chunk];
        const unsigned int woff = wo[chunk];                                  // actives before word
        const unsigned int iwoff = (unsigned int)(wi0 + chunk) * 64u - woff;  // inactives before

        // ---- emit: group g handles rows g, g+16, g+32, g+48 (branchless)
#pragma unroll
        for (int i = 0; i < 4; ++i) {
            const int r = g + 16 * i;
            const unsigned long long before = wflag & ((1ull << r) - 1ull);  // r==0 -> 0
            const unsigned int ab = (unsigned int)__popcll(before);
            const bool act = (wflag >> r) & 1ull;
            const size_t arow = (size_t)(woff + ab);
            const size_t zrow = (size_t)(NSITES - 1) - (size_t)(iwoff + ((unsigned int)r - ab));
            const size_t row = act ? arow : zrow;
            f32x4 v;
            v.x = tile[r * 65 + 4 * l16 + 0];
            v.y = tile[r * 65 + 4 * l16 + 1];
            v.z = tile[r * 65 + 4 * l16 + 2];
            v.w = tile[r * 65 + 4 * l16 + 3];
            const f32x4 zv = {0.f, 0.f, 0.f, 0.f};
            if (!act) v = zv;
            __builtin_nontemporal_store(
                v, reinterpret_cast<f32x4*>(out + row * CC + 4 * l16));
        }

        if (chunk < 3) __syncthreads();  // protect tile before next staging
    }
}

extern "C" void kernel_launch(void* const* d_in, const int* in_sizes, int n_in,
                              void* d_out, int out_size, void* d_ws, size_t ws_size,
                              hipStream_t stream) {
    (void)in_sizes; (void)n_in; (void)out_size; (void)ws_size;
    const float* x = (const float*)d_in[0];
    float* out = (float*)d_out;

    char* ws = (char*)d_ws;
    unsigned long long* flags = (unsigned long long*)ws;          // 64 KiB
    unsigned int* blockSum = (unsigned int*)(ws + 65536);         // 2 KiB

    float* out_count_f = out + (size_t)NSITES * CC;  // second tuple output

    hipLaunchKernelGGL(k_flags, dim3(NSITES / 1024), dim3(256), 0, stream, x, flags, blockSum);
    hipLaunchKernelGGL(k_scatter, dim3(NWORDS / 4), dim3(256), 0, stream, x, flags, blockSum,
                       out, out_count_f);
}